// Round 1
// baseline (66864.972 us; speedup 1.0000x reference)
//
#include <hip/hip_runtime.h>

#define SEQ  512
#define IDIM 256
#define H    1024
#define NC   128
#define B    256

#define BM 32
#define KC 128

__device__ __forceinline__ float sig(float x) { return 1.0f / (1.0f + __expf(-x)); }

// ---------------- token tables: FF/II/OO = emb@W*x.T + b*, G = sigmoid(emb@Wcx.T + bc) ----
__global__ __launch_bounds__(256) void tables_kernel(
    const float* __restrict__ emb,
    const float* __restrict__ Wcx, const float* __restrict__ bc,
    const float* __restrict__ Wix, const float* __restrict__ bi,
    const float* __restrict__ Wfx, const float* __restrict__ bf,
    const float* __restrict__ Wox, const float* __restrict__ bo,
    float* __restrict__ FF, float* __restrict__ II,
    float* __restrict__ OO, float* __restrict__ G)
{
    const int k = blockIdx.x;                       // class 0..127
    const int h = blockIdx.y * 256 + threadIdx.x;   // 0..1023
    __shared__ float e[IDIM];
    e[threadIdx.x] = emb[k * IDIM + threadIdx.x];
    __syncthreads();
    const float4* e4  = (const float4*)e;
    const float4* wf4 = (const float4*)(Wfx + (size_t)h * IDIM);
    const float4* wi4 = (const float4*)(Wix + (size_t)h * IDIM);
    const float4* wo4 = (const float4*)(Wox + (size_t)h * IDIM);
    const float4* wc4 = (const float4*)(Wcx + (size_t)h * IDIM);
    float aF = 0.f, aI = 0.f, aO = 0.f, aC = 0.f;
#pragma unroll 4
    for (int i = 0; i < IDIM / 4; i++) {
        float4 ev = e4[i];
        float4 a = wf4[i]; aF += ev.x * a.x + ev.y * a.y + ev.z * a.z + ev.w * a.w;
        float4 b = wi4[i]; aI += ev.x * b.x + ev.y * b.y + ev.z * b.z + ev.w * b.w;
        float4 c = wo4[i]; aO += ev.x * c.x + ev.y * c.y + ev.z * c.z + ev.w * c.w;
        float4 d = wc4[i]; aC += ev.x * d.x + ev.y * d.y + ev.z * d.z + ev.w * d.w;
    }
    const int o = k * H + h;
    FF[o] = aF + bf[h];
    II[o] = aI + bi[h];
    OO[o] = aO + bo[h];
    G[o]  = sig(aC + bc[h]);
}

// ---------------- one recurrence step: c_new = G[tok]*sig(II[tok]+c@Wih.T) + c*sig(FF[tok]+c@Wfh.T)
// grid (8 row-tiles, 32 col-tiles), block 256. Each thread: 2 rows x 2 cols x 2 gates.
__global__ __launch_bounds__(256) void step_kernel(
    const float* __restrict__ c_old, float* __restrict__ c_new,
    const float* __restrict__ Wfh, const float* __restrict__ Wih,
    const float* __restrict__ FF, const float* __restrict__ II,
    const float* __restrict__ G, const int* __restrict__ x, int s)
{
    const int row0 = blockIdx.x * BM;
    const int col0 = blockIdx.y * 32;
    const int tid = threadIdx.x;
    const int tx = tid & 15;        // col-pair
    const int ty = tid >> 4;        // row-pair
    const int r0 = row0 + ty * 2;
    const int h0 = col0 + tx * 2;

    __shared__ float cs[BM][KC + 4];   // +4 pad rotates banks across rows

    float af00 = 0.f, af01 = 0.f, af10 = 0.f, af11 = 0.f;
    float ai00 = 0.f, ai01 = 0.f, ai10 = 0.f, ai11 = 0.f;

    const float* wf0p = Wfh + (size_t)h0 * H;
    const float* wf1p = Wfh + (size_t)(h0 + 1) * H;
    const float* wi0p = Wih + (size_t)h0 * H;
    const float* wi1p = Wih + (size_t)(h0 + 1) * H;

    for (int kc = 0; kc < H; kc += KC) {
        __syncthreads();
        // stage 32x128 c-tile: 1024 float4, 4 per thread, coalesced
#pragma unroll
        for (int j = 0; j < 4; j++) {
            int idx = tid + j * 256;         // 0..1023
            int r   = idx >> 5;              // 32 float4 per row
            int c4  = idx & 31;
            float4 v = *(const float4*)(c_old + (size_t)(row0 + r) * H + kc + c4 * 4);
            *(float4*)&cs[r][c4 * 4] = v;
        }
        __syncthreads();
#pragma unroll 4
        for (int k = 0; k < KC; k += 4) {
            float4 ca = *(const float4*)&cs[ty * 2][k];
            float4 cb = *(const float4*)&cs[ty * 2 + 1][k];
            float4 f0 = *(const float4*)(wf0p + kc + k);
            float4 f1 = *(const float4*)(wf1p + kc + k);
            float4 i0 = *(const float4*)(wi0p + kc + k);
            float4 i1 = *(const float4*)(wi1p + kc + k);
            af00 += ca.x * f0.x + ca.y * f0.y + ca.z * f0.z + ca.w * f0.w;
            af01 += ca.x * f1.x + ca.y * f1.y + ca.z * f1.z + ca.w * f1.w;
            af10 += cb.x * f0.x + cb.y * f0.y + cb.z * f0.z + cb.w * f0.w;
            af11 += cb.x * f1.x + cb.y * f1.y + cb.z * f1.z + cb.w * f1.w;
            ai00 += ca.x * i0.x + ca.y * i0.y + ca.z * i0.z + ca.w * i0.w;
            ai01 += ca.x * i1.x + ca.y * i1.y + ca.z * i1.z + ca.w * i1.w;
            ai10 += cb.x * i0.x + cb.y * i0.y + cb.z * i0.z + cb.w * i0.w;
            ai11 += cb.x * i1.x + cb.y * i1.y + cb.z * i1.z + cb.w * i1.w;
        }
    }

    const int tokA = x[(size_t)r0 * SEQ + s];
    const int tokB = x[(size_t)(r0 + 1) * SEQ + s];
    {
        float f = sig(FF[tokA * H + h0] + af00);
        float i = sig(II[tokA * H + h0] + ai00);
        c_new[(size_t)r0 * H + h0] = G[tokA * H + h0] * i + c_old[(size_t)r0 * H + h0] * f;
    }
    {
        float f = sig(FF[tokA * H + h0 + 1] + af01);
        float i = sig(II[tokA * H + h0 + 1] + ai01);
        c_new[(size_t)r0 * H + h0 + 1] = G[tokA * H + h0 + 1] * i + c_old[(size_t)r0 * H + h0 + 1] * f;
    }
    {
        float f = sig(FF[tokB * H + h0] + af10);
        float i = sig(II[tokB * H + h0] + ai10);
        c_new[(size_t)(r0 + 1) * H + h0] = G[tokB * H + h0] * i + c_old[(size_t)(r0 + 1) * H + h0] * f;
    }
    {
        float f = sig(FF[tokB * H + h0 + 1] + af11);
        float i = sig(II[tokB * H + h0 + 1] + ai11);
        c_new[(size_t)(r0 + 1) * H + h0 + 1] = G[tokB * H + h0 + 1] * i + c_old[(size_t)(r0 + 1) * H + h0 + 1] * f;
    }
}

// ---------------- final h = tanh(c_512) * sig(OO[tok_511] + c_511 @ Woh.T) ----------------
__global__ __launch_bounds__(256) void hfinal_kernel(
    const float* __restrict__ c_prev, const float* __restrict__ c_fin,
    const float* __restrict__ Woh, const float* __restrict__ OO,
    const int* __restrict__ x, float* __restrict__ hout)
{
    const int row0 = blockIdx.x * BM;
    const int col0 = blockIdx.y * 32;
    const int tid = threadIdx.x;
    const int tx = tid & 15;
    const int ty = tid >> 4;
    const int r0 = row0 + ty * 2;
    const int h0 = col0 + tx * 2;

    __shared__ float cs[BM][KC + 4];

    float a00 = 0.f, a01 = 0.f, a10 = 0.f, a11 = 0.f;
    const float* w0p = Woh + (size_t)h0 * H;
    const float* w1p = Woh + (size_t)(h0 + 1) * H;

    for (int kc = 0; kc < H; kc += KC) {
        __syncthreads();
#pragma unroll
        for (int j = 0; j < 4; j++) {
            int idx = tid + j * 256;
            int r   = idx >> 5;
            int c4  = idx & 31;
            float4 v = *(const float4*)(c_prev + (size_t)(row0 + r) * H + kc + c4 * 4);
            *(float4*)&cs[r][c4 * 4] = v;
        }
        __syncthreads();
#pragma unroll 4
        for (int k = 0; k < KC; k += 4) {
            float4 ca = *(const float4*)&cs[ty * 2][k];
            float4 cb = *(const float4*)&cs[ty * 2 + 1][k];
            float4 w0 = *(const float4*)(w0p + kc + k);
            float4 w1 = *(const float4*)(w1p + kc + k);
            a00 += ca.x * w0.x + ca.y * w0.y + ca.z * w0.z + ca.w * w0.w;
            a01 += ca.x * w1.x + ca.y * w1.y + ca.z * w1.z + ca.w * w1.w;
            a10 += cb.x * w0.x + cb.y * w0.y + cb.z * w0.z + cb.w * w0.w;
            a11 += cb.x * w1.x + cb.y * w1.y + cb.z * w1.z + cb.w * w1.w;
        }
    }

    const int tokA = x[(size_t)r0 * SEQ + (SEQ - 1)];
    const int tokB = x[(size_t)(r0 + 1) * SEQ + (SEQ - 1)];
    hout[(size_t)r0 * H + h0]           = tanhf(c_fin[(size_t)r0 * H + h0])           * sig(OO[tokA * H + h0] + a00);
    hout[(size_t)r0 * H + h0 + 1]       = tanhf(c_fin[(size_t)r0 * H + h0 + 1])       * sig(OO[tokA * H + h0 + 1] + a01);
    hout[(size_t)(r0 + 1) * H + h0]     = tanhf(c_fin[(size_t)(r0 + 1) * H + h0])     * sig(OO[tokB * H + h0] + a10);
    hout[(size_t)(r0 + 1) * H + h0 + 1] = tanhf(c_fin[(size_t)(r0 + 1) * H + h0 + 1]) * sig(OO[tokB * H + h0 + 1] + a11);
}

// ---------------- p = h @ Wph.T + bp ; out = log_softmax(p) -------------------------------
__global__ __launch_bounds__(128) void out_kernel(
    const float* __restrict__ hbuf, const float* __restrict__ Wph,
    const float* __restrict__ bp, float* __restrict__ out)
{
    const int b = blockIdx.x;
    const int j = threadIdx.x;     // 0..127
    __shared__ float hs[H];
    for (int t = j; t < H; t += 128) hs[t] = hbuf[(size_t)b * H + t];
    __syncthreads();
    const float4* w4 = (const float4*)(Wph + (size_t)j * H);
    const float4* h4 = (const float4*)hs;
    float acc = bp[j];
#pragma unroll 4
    for (int k = 0; k < H / 4; k++) {
        float4 a = w4[k], v = h4[k];
        acc += a.x * v.x + a.y * v.y + a.z * v.z + a.w * v.w;
    }
    __shared__ float red[128];
    red[j] = acc; __syncthreads();
    for (int off = 64; off > 0; off >>= 1) { if (j < off) red[j] = fmaxf(red[j], red[j + off]); __syncthreads(); }
    float m = red[0]; __syncthreads();
    red[j] = __expf(acc - m); __syncthreads();
    for (int off = 64; off > 0; off >>= 1) { if (j < off) red[j] += red[j + off]; __syncthreads(); }
    float lse = m + __logf(red[0]);
    out[(size_t)b * NC + j] = acc - lse;
}

extern "C" void kernel_launch(void* const* d_in, const int* in_sizes, int n_in,
                              void* d_out, int out_size, void* d_ws, size_t ws_size,
                              hipStream_t stream)
{
    const int*   x   = (const int*)d_in[0];
    const float* emb = (const float*)d_in[1];
    const float* Wcx = (const float*)d_in[2];
    const float* bc  = (const float*)d_in[3];
    const float* Wix = (const float*)d_in[4];
    const float* Wih = (const float*)d_in[5];
    const float* bi  = (const float*)d_in[6];
    const float* Wfx = (const float*)d_in[7];
    const float* Wfh = (const float*)d_in[8];
    const float* bf  = (const float*)d_in[9];
    const float* Wox = (const float*)d_in[10];
    const float* Woh = (const float*)d_in[11];
    const float* bo  = (const float*)d_in[12];
    const float* Wph = (const float*)d_in[13];
    const float* bp  = (const float*)d_in[14];
    float* out = (float*)d_out;

    float* ws  = (float*)d_ws;
    float* FF  = ws;                 // 128*1024
    float* II  = FF + NC * H;
    float* OO  = II + NC * H;
    float* G   = OO + NC * H;
    float* cb0 = G + NC * H;         // 256*1024
    float* cb1 = cb0 + B * H;
    float* hb  = cb1 + B * H;

    // c_0 = 0 (ws is poisoned 0xAA before every call)
    hipMemsetAsync(cb0, 0, (size_t)B * H * sizeof(float), stream);

    tables_kernel<<<dim3(NC, 4), 256, 0, stream>>>(emb, Wcx, bc, Wix, bi, Wfx, bf, Wox, bo,
                                                   FF, II, OO, G);

    for (int s = 0; s < SEQ; s++) {
        const float* co = (s & 1) ? cb1 : cb0;
        float*       cn = (s & 1) ? cb0 : cb1;
        step_kernel<<<dim3(8, 32), 256, 0, stream>>>(co, cn, Wfh, Wih, FF, II, G, x, s);
    }
    // after loop: c_512 in cb0, c_511 in cb1
    hfinal_kernel<<<dim3(8, 32), 256, 0, stream>>>(cb1, cb0, Woh, OO, x, hb);
    out_kernel<<<B, 128, 0, stream>>>(hb, Wph, bp, out);
}

// Round 2
// 19566.841 us; speedup vs baseline: 3.4173x; 3.4173x over previous
//
#include <hip/hip_runtime.h>

#define SEQ  512
#define IDIM 256
#define H    1024
#define NC   128
#define B    256
#define NBLK 256

typedef __attribute__((ext_vector_type(8))) short bh8;
typedef __attribute__((ext_vector_type(4))) float f4;

__device__ __forceinline__ float sigf(float x) { return 1.0f / (1.0f + __expf(-x)); }

__device__ __forceinline__ unsigned short bf16r(float v) {
    unsigned u = __builtin_bit_cast(unsigned, v);
    u += 0x7fffu + ((u >> 16) & 1u);
    return (unsigned short)(u >> 16);
}

// ---------------- token tables: FF/II/OO = emb@W*x.T + b*, G = sigmoid(emb@Wcx.T + bc) ----
__global__ __launch_bounds__(256) void tables_kernel(
    const float* __restrict__ emb,
    const float* __restrict__ Wcx, const float* __restrict__ bc,
    const float* __restrict__ Wix, const float* __restrict__ bi,
    const float* __restrict__ Wfx, const float* __restrict__ bf,
    const float* __restrict__ Wox, const float* __restrict__ bo,
    float* __restrict__ FF, float* __restrict__ II,
    float* __restrict__ OO, float* __restrict__ G)
{
    const int k = blockIdx.x;
    const int h = blockIdx.y * 256 + threadIdx.x;
    __shared__ float e[IDIM];
    e[threadIdx.x] = emb[k * IDIM + threadIdx.x];
    __syncthreads();
    const float4* e4  = (const float4*)e;
    const float4* wf4 = (const float4*)(Wfx + (size_t)h * IDIM);
    const float4* wi4 = (const float4*)(Wix + (size_t)h * IDIM);
    const float4* wo4 = (const float4*)(Wox + (size_t)h * IDIM);
    const float4* wc4 = (const float4*)(Wcx + (size_t)h * IDIM);
    float aF = 0.f, aI = 0.f, aO = 0.f, aC = 0.f;
#pragma unroll 4
    for (int i = 0; i < IDIM / 4; i++) {
        float4 ev = e4[i];
        float4 a = wf4[i]; aF += ev.x * a.x + ev.y * a.y + ev.z * a.z + ev.w * a.w;
        float4 b = wi4[i]; aI += ev.x * b.x + ev.y * b.y + ev.z * b.z + ev.w * b.w;
        float4 c = wo4[i]; aO += ev.x * c.x + ev.y * c.y + ev.z * c.z + ev.w * c.w;
        float4 d = wc4[i]; aC += ev.x * d.x + ev.y * d.y + ev.z * d.z + ev.w * d.w;
    }
    const int o = k * H + h;
    FF[o] = aF + bf[h];
    II[o] = aI + bi[h];
    OO[o] = aO + bo[h];
    G[o]  = sigf(aC + bc[h]);
}

// ---------------- weight fp32 -> bf16 swizzled for MFMA B-fragments -----------------------
// block (nb, kb): nb = h/16, kb = k/32. lane l holds W[nb*16 + (l&15)][kb*32 + (l>>4)*8 + j]
// at bf16 offset (nb*32 + kb)*512 + l*8 + j  -> each B-frag load = contiguous 16 B per lane.
__global__ __launch_bounds__(256) void swz_kernel(const float* __restrict__ W,
                                                  unsigned short* __restrict__ D)
{
    int g = blockIdx.x * 256 + threadIdx.x;     // 0..131071
    int h  = g >> 7;
    int kc = (g & 127) << 3;
    const float4* s = (const float4*)(W + (size_t)h * H + kc);
    float4 a = s[0], b = s[1];
    unsigned short tmp[8] = { bf16r(a.x), bf16r(a.y), bf16r(a.z), bf16r(a.w),
                              bf16r(b.x), bf16r(b.y), bf16r(b.z), bf16r(b.w) };
    int nb = h >> 4, kb = kc >> 5, quad = (kc >> 3) & 3;
    int lane = (h & 15) + (quad << 4);
    bh8 v;
#pragma unroll
    for (int j = 0; j < 8; j++) v[j] = (short)tmp[j];
    *(bh8*)(D + (size_t)((nb * 32 + kb) * 512 + lane * 8)) = v;
}

// ---------------- persistent recurrence kernel --------------------------------------------
__global__ __launch_bounds__(256) void persist_kernel(
    const unsigned short* __restrict__ Wf, const unsigned short* __restrict__ Wi,
    const unsigned short* __restrict__ Wo,
    const float* __restrict__ FF, const float* __restrict__ II,
    const float* __restrict__ OO, const float* __restrict__ G,
    const int* __restrict__ x,
    unsigned short* c16a, unsigned short* c16b,
    float* __restrict__ hb, int* bar)
{
    const int blk = blockIdx.x;
    const int rt = blk >> 5;            // row-tile 0..7  (32 batch rows)
    const int nt = blk & 31;            // col-tile 0..31 (32 h cols); nt%8 tracks XCD -> L2 locality
    const int tid  = threadIdx.x;
    const int wave = tid >> 6;
    const int lane = tid & 63;
    const int msub = wave & 1, nsub = wave >> 1;
    const int l15 = lane & 15, quad = lane >> 4;

    __shared__ unsigned short cs[32 * 1024];   // 64 KB: 32 rows x 1024 bf16, XOR-swizzled 16B chunks

    const int row0 = rt * 32;
    const int arow = msub * 16 + l15;          // LDS row for A-fragment
    const int abase = arow * 1024;
    const int asw = arow & 7;
    const int hcol = nt * 32 + nsub * 16 + l15;
    const int nb = nt * 2 + nsub;

    const unsigned short* wfp = Wf + (size_t)nb * 32 * 512 + (size_t)lane * 8;
    const unsigned short* wip = Wi + (size_t)nb * 32 * 512 + (size_t)lane * 8;
    const unsigned short* wop = Wo + (size_t)nb * 32 * 512 + (size_t)lane * 8;

    float cn_keep[4] = {0.f, 0.f, 0.f, 0.f};   // fp32 cell state lives in registers

    for (int s = 0; s < SEQ; s++) {
        const unsigned short* cur16 = (s & 1) ? c16b : c16a;
        unsigned short*       nxt16 = (s & 1) ? c16a : c16b;

        // stage 32 rows x 1024 bf16 of c into LDS (coalesced 16 B/lane, xor-swizzle)
#pragma unroll
        for (int i = 0; i < 16; i++) {
            int chunk = i * 256 + tid;
            int row = chunk >> 7;
            int c8  = chunk & 127;
            int c8s = c8 ^ (row & 7);
            bh8 v = *(const bh8*)(cur16 + (size_t)(row0 + row) * H + c8 * 8);
            *(bh8*)(cs + row * 1024 + c8s * 8) = v;
        }
        __syncthreads();

        f4 accF = {0.f, 0.f, 0.f, 0.f}, accI = {0.f, 0.f, 0.f, 0.f};
#pragma unroll 4
        for (int kt = 0; kt < 32; kt++) {
            bh8 a  = *(const bh8*)(cs + abase + (((kt * 4 + quad) ^ asw) << 3));
            bh8 bf = *(const bh8*)(wfp + (size_t)kt * 512);
            bh8 bi = *(const bh8*)(wip + (size_t)kt * 512);
            accF = __builtin_amdgcn_mfma_f32_16x16x32_bf16(a, bf, accF, 0, 0, 0);
            accI = __builtin_amdgcn_mfma_f32_16x16x32_bf16(a, bi, accI, 0, 0, 0);
        }

        // epilogue: C/D layout col=lane&15, row=quad*4+reg
#pragma unroll
        for (int r = 0; r < 4; r++) {
            int b = row0 + msub * 16 + quad * 4 + r;
            int tok = x[b * SEQ + s];
            float f = sigf(FF[tok * H + hcol] + accF[r]);
            float i = sigf(II[tok * H + hcol] + accI[r]);
            float cn = G[tok * H + hcol] * i + cn_keep[r] * f;
            cn_keep[r] = cn;
            nxt16[(size_t)b * H + hcol] = bf16r(cn);
        }

        if (s < SEQ - 1) {
            // sense-reversing grid barrier (all 256 blocks co-resident: 64 KB LDS, 256 grid)
            __syncthreads();                     // drains vmcnt -> our stores reached L2
            if (tid == 0) {
                int target = 1 - (s & 1);
                __threadfence();                 // release: flush to device visibility
                if (atomicAdd(&bar[0], 1) == NBLK - 1) {
                    __hip_atomic_store(&bar[0], 0, __ATOMIC_RELAXED, __HIP_MEMORY_SCOPE_AGENT);
                    __hip_atomic_store(&bar[1], target, __ATOMIC_RELEASE, __HIP_MEMORY_SCOPE_AGENT);
                } else {
                    int guard = 0;
                    while (__hip_atomic_load(&bar[1], __ATOMIC_RELAXED, __HIP_MEMORY_SCOPE_AGENT) != target) {
                        __builtin_amdgcn_s_sleep(2);
                        if (++guard > (1 << 24)) break;   // hang-bailout (debug only)
                    }
                }
            }
            __syncthreads();
            __threadfence();                     // acquire: invalidate L1 before reading others' c
        }
    }

    // o-gate: c_511 is still staged in LDS (it was this step's A input)
    f4 accO = {0.f, 0.f, 0.f, 0.f};
#pragma unroll 4
    for (int kt = 0; kt < 32; kt++) {
        bh8 a  = *(const bh8*)(cs + abase + (((kt * 4 + quad) ^ asw) << 3));
        bh8 bo = *(const bh8*)(wop + (size_t)kt * 512);
        accO = __builtin_amdgcn_mfma_f32_16x16x32_bf16(a, bo, accO, 0, 0, 0);
    }
#pragma unroll
    for (int r = 0; r < 4; r++) {
        int b = row0 + msub * 16 + quad * 4 + r;
        int tok = x[b * SEQ + (SEQ - 1)];
        float o = sigf(OO[tok * H + hcol] + accO[r]);
        hb[(size_t)b * H + hcol] = tanhf(cn_keep[r]) * o;
    }
}

// ---------------- p = h @ Wph.T + bp ; out = log_softmax(p) -------------------------------
__global__ __launch_bounds__(128) void out_kernel(
    const float* __restrict__ hbuf, const float* __restrict__ Wph,
    const float* __restrict__ bp, float* __restrict__ out)
{
    const int b = blockIdx.x;
    const int j = threadIdx.x;
    __shared__ float hs[H];
    for (int t = j; t < H; t += 128) hs[t] = hbuf[(size_t)b * H + t];
    __syncthreads();
    const float4* w4 = (const float4*)(Wph + (size_t)j * H);
    const float4* h4 = (const float4*)hs;
    float acc = bp[j];
#pragma unroll 4
    for (int k = 0; k < H / 4; k++) {
        float4 a = w4[k], v = h4[k];
        acc += a.x * v.x + a.y * v.y + a.z * v.z + a.w * v.w;
    }
    __shared__ float red[128];
    red[j] = acc; __syncthreads();
    for (int off = 64; off > 0; off >>= 1) { if (j < off) red[j] = fmaxf(red[j], red[j + off]); __syncthreads(); }
    float m = red[0]; __syncthreads();
    red[j] = __expf(acc - m); __syncthreads();
    for (int off = 64; off > 0; off >>= 1) { if (j < off) red[j] += red[j + off]; __syncthreads(); }
    float lse = m + __logf(red[0]);
    out[(size_t)b * NC + j] = acc - lse;
}

extern "C" void kernel_launch(void* const* d_in, const int* in_sizes, int n_in,
                              void* d_out, int out_size, void* d_ws, size_t ws_size,
                              hipStream_t stream)
{
    const int*   x   = (const int*)d_in[0];
    const float* emb = (const float*)d_in[1];
    const float* Wcx = (const float*)d_in[2];
    const float* bc  = (const float*)d_in[3];
    const float* Wix = (const float*)d_in[4];
    const float* Wih = (const float*)d_in[5];
    const float* bi  = (const float*)d_in[6];
    const float* Wfx = (const float*)d_in[7];
    const float* Wfh = (const float*)d_in[8];
    const float* bf  = (const float*)d_in[9];
    const float* Wox = (const float*)d_in[10];
    const float* Woh = (const float*)d_in[11];
    const float* bo  = (const float*)d_in[12];
    const float* Wph = (const float*)d_in[13];
    const float* bp  = (const float*)d_in[14];
    float* out = (float*)d_out;

    char* wsb = (char*)d_ws;
    float* FF = (float*)(wsb + 0);                         // 512 KB
    float* II = (float*)(wsb + (512 << 10));
    float* OO = (float*)(wsb + (1024 << 10));
    float* G  = (float*)(wsb + (1536 << 10));
    float* hb = (float*)(wsb + (2048 << 10));              // 1 MB
    int*   bar = (int*)(wsb + (3072 << 10));               // 64 B
    unsigned short* Wf_sw = (unsigned short*)(wsb + (4096 << 10));   // 2 MB each
    unsigned short* Wi_sw = (unsigned short*)(wsb + (6144 << 10));
    unsigned short* Wo_sw = (unsigned short*)(wsb + (8192 << 10));
    unsigned short* c16a  = (unsigned short*)(wsb + (10240 << 10));  // 512 KB each
    unsigned short* c16b  = (unsigned short*)(wsb + (10752 << 10));

    hipMemsetAsync(c16a, 0, (size_t)B * H * sizeof(unsigned short), stream);  // c_0 = 0
    hipMemsetAsync(bar, 0, 64, stream);                                       // barrier state

    tables_kernel<<<dim3(NC, 4), 256, 0, stream>>>(emb, Wcx, bc, Wix, bi, Wfx, bf, Wox, bo,
                                                   FF, II, OO, G);
    swz_kernel<<<512, 256, 0, stream>>>(Wfh, Wf_sw);
    swz_kernel<<<512, 256, 0, stream>>>(Wih, Wi_sw);
    swz_kernel<<<512, 256, 0, stream>>>(Woh, Wo_sw);

    persist_kernel<<<NBLK, 256, 0, stream>>>(Wf_sw, Wi_sw, Wo_sw, FF, II, OO, G, x,
                                             c16a, c16b, hb, bar);

    out_kernel<<<B, 128, 0, stream>>>(hb, Wph, bp, out);
}

// Round 3
// 8993.962 us; speedup vs baseline: 7.4344x; 2.1756x over previous
//
#include <hip/hip_runtime.h>

#define SEQ  512
#define IDIM 256
#define H    1024
#define NC   128
#define B    256
#define NBLK 256

typedef __attribute__((ext_vector_type(8))) short bh8;
typedef __attribute__((ext_vector_type(4))) float f4;

__device__ __forceinline__ float sigf(float x) { return 1.0f / (1.0f + __expf(-x)); }

__device__ __forceinline__ unsigned short bf16r(float v) {
    unsigned u = __builtin_bit_cast(unsigned, v);
    u += 0x7fffu + ((u >> 16) & 1u);
    return (unsigned short)(u >> 16);
}

// ---------------- token tables: FF/II/OO = emb@W*x.T + b*, G = sigmoid(emb@Wcx.T + bc) ----
__global__ __launch_bounds__(256) void tables_kernel(
    const float* __restrict__ emb,
    const float* __restrict__ Wcx, const float* __restrict__ bc,
    const float* __restrict__ Wix, const float* __restrict__ bi,
    const float* __restrict__ Wfx, const float* __restrict__ bf,
    const float* __restrict__ Wox, const float* __restrict__ bo,
    float* __restrict__ FF, float* __restrict__ II,
    float* __restrict__ OO, float* __restrict__ G)
{
    const int k = blockIdx.x;
    const int h = blockIdx.y * 256 + threadIdx.x;
    __shared__ float e[IDIM];
    e[threadIdx.x] = emb[k * IDIM + threadIdx.x];
    __syncthreads();
    const float4* e4  = (const float4*)e;
    const float4* wf4 = (const float4*)(Wfx + (size_t)h * IDIM);
    const float4* wi4 = (const float4*)(Wix + (size_t)h * IDIM);
    const float4* wo4 = (const float4*)(Wox + (size_t)h * IDIM);
    const float4* wc4 = (const float4*)(Wcx + (size_t)h * IDIM);
    float aF = 0.f, aI = 0.f, aO = 0.f, aC = 0.f;
#pragma unroll 4
    for (int i = 0; i < IDIM / 4; i++) {
        float4 ev = e4[i];
        float4 a = wf4[i]; aF += ev.x * a.x + ev.y * a.y + ev.z * a.z + ev.w * a.w;
        float4 b = wi4[i]; aI += ev.x * b.x + ev.y * b.y + ev.z * b.z + ev.w * b.w;
        float4 c = wo4[i]; aO += ev.x * c.x + ev.y * c.y + ev.z * c.z + ev.w * c.w;
        float4 d = wc4[i]; aC += ev.x * d.x + ev.y * d.y + ev.z * d.z + ev.w * d.w;
    }
    const int o = k * H + h;
    FF[o] = aF + bf[h];
    II[o] = aI + bi[h];
    OO[o] = aO + bo[h];
    G[o]  = sigf(aC + bc[h]);
}

// ---------------- weight fp32 -> bf16 swizzled for MFMA B-fragments -----------------------
__global__ __launch_bounds__(256) void swz_kernel(const float* __restrict__ W,
                                                  unsigned short* __restrict__ D)
{
    int g = blockIdx.x * 256 + threadIdx.x;     // 0..131071
    int h  = g >> 7;
    int kc = (g & 127) << 3;
    const float4* s = (const float4*)(W + (size_t)h * H + kc);
    float4 a = s[0], b = s[1];
    unsigned short tmp[8] = { bf16r(a.x), bf16r(a.y), bf16r(a.z), bf16r(a.w),
                              bf16r(b.x), bf16r(b.y), bf16r(b.z), bf16r(b.w) };
    int nb = h >> 4, kb = kc >> 5, quad = (kc >> 3) & 3;
    int lane = (h & 15) + (quad << 4);
    bh8 v;
#pragma unroll
    for (int j = 0; j < 8; j++) v[j] = (short)tmp[j];
    *(bh8*)(D + (size_t)((nb * 32 + kb) * 512 + lane * 8)) = v;
}

// ---------------- persistent recurrence kernel --------------------------------------------
__global__ __launch_bounds__(256) void persist_kernel(
    const unsigned short* __restrict__ Wf, const unsigned short* __restrict__ Wi,
    const unsigned short* __restrict__ Wo,
    const float* __restrict__ FF, const float* __restrict__ II,
    const float* __restrict__ OO, const float* __restrict__ G,
    const int* __restrict__ x,
    unsigned short* c16a, unsigned short* c16b,
    float* __restrict__ hb, int* flags)
{
    const int blk = blockIdx.x;
    const int rt = blk >> 5;            // row-tile 0..7  (32 batch rows)
    const int nt = blk & 31;            // col-tile 0..31 (32 h cols)
    const int tid  = threadIdx.x;
    const int wave = tid >> 6;
    const int lane = tid & 63;
    const int msub = wave & 1, nsub = wave >> 1;
    const int l15 = lane & 15, quad = lane >> 4;

    __shared__ unsigned short cs[32 * 1024];   // 64 KB, XOR-swizzled 16B granules

    const int row0 = rt * 32;
    const int arow = msub * 16 + l15;
    const int abase = arow * 1024;
    const int asw = arow & 7;
    const int hcol = nt * 32 + nsub * 16 + l15;
    const int nb = nt * 2 + nsub;

    const unsigned short* wfp = Wf + (size_t)nb * 32 * 512 + (size_t)lane * 8;
    const unsigned short* wip = Wi + (size_t)nb * 32 * 512 + (size_t)lane * 8;
    const unsigned short* wop = Wo + (size_t)nb * 32 * 512 + (size_t)lane * 8;

    float cn_keep[4] = {0.f, 0.f, 0.f, 0.f};   // fp32 cell state in registers

    for (int s = 0; s < SEQ; s++) {
        const unsigned short* cur16 = (s & 1) ? c16b : c16a;
        unsigned short*       nxt16 = (s & 1) ? c16a : c16b;

        // stage 32 rows x 1024 bf16 via agent-scope (LLC-direct) 8B loads, coalesced
#pragma unroll
        for (int i = 0; i < 32; i++) {
            int unit = i * 256 + tid;            // 8192 8-byte units
            int row  = unit >> 8;                // 256 units per row
            int u8   = unit & 255;
            int g    = u8 >> 1;                  // 16B granule
            int half = u8 & 1;
            unsigned long long v = __hip_atomic_load(
                (const unsigned long long*)(cur16 + (size_t)(row0 + row) * H + u8 * 4),
                __ATOMIC_RELAXED, __HIP_MEMORY_SCOPE_AGENT);
            *(unsigned long long*)(cs + row * 1024 + ((g ^ (row & 7)) << 3) + (half << 2)) = v;
        }

        // prefetch token-table values (overlaps with MFMA below)
        float ffv[4], iiv[4], ggv[4];
#pragma unroll
        for (int r = 0; r < 4; r++) {
            int b = row0 + msub * 16 + quad * 4 + r;
            int tok = x[b * SEQ + s];
            ffv[r] = FF[tok * H + hcol];
            iiv[r] = II[tok * H + hcol];
            ggv[r] = G[tok * H + hcol];
        }
        __syncthreads();

        f4 accF = {0.f, 0.f, 0.f, 0.f}, accI = {0.f, 0.f, 0.f, 0.f};
#pragma unroll 4
        for (int kt = 0; kt < 32; kt++) {
            bh8 a  = *(const bh8*)(cs + abase + (((kt * 4 + quad) ^ asw) << 3));
            bh8 bf = *(const bh8*)(wfp + (size_t)kt * 512);
            bh8 bi = *(const bh8*)(wip + (size_t)kt * 512);
            accF = __builtin_amdgcn_mfma_f32_16x16x32_bf16(a, bf, accF, 0, 0, 0);
            accI = __builtin_amdgcn_mfma_f32_16x16x32_bf16(a, bi, accI, 0, 0, 0);
        }

        // epilogue: C/D layout col=lane&15, row=quad*4+reg; pack 2 cols/dword via shfl
#pragma unroll
        for (int r = 0; r < 4; r++) {
            int b = row0 + msub * 16 + quad * 4 + r;
            float f = sigf(ffv[r] + accF[r]);
            float i = sigf(iiv[r] + accI[r]);
            float cn = ggv[r] * i + cn_keep[r] * f;
            cn_keep[r] = cn;
            unsigned us = bf16r(cn);
            unsigned ot = (unsigned)__shfl_xor((int)us, 1);
            if ((lane & 1) == 0) {
                unsigned dw = us | (ot << 16);
                __hip_atomic_store((unsigned*)(nxt16 + (size_t)b * H + hcol), dw,
                                   __ATOMIC_RELAXED, __HIP_MEMORY_SCOPE_AGENT);
            }
        }

        if (s < SEQ - 1) {
            __syncthreads();   // all waves' sc1 stores drained (implicit vmcnt(0) at barrier)
            if (tid < 64) {
                if (tid == 0)
                    __hip_atomic_store(&flags[blk], s + 1, __ATOMIC_RELEASE,
                                       __HIP_MEMORY_SCOPE_AGENT);
                const int target = s + 1;
                int guard = 0;
                for (;;) {
                    int f0 = __hip_atomic_load(&flags[tid],       __ATOMIC_RELAXED, __HIP_MEMORY_SCOPE_AGENT);
                    int f1 = __hip_atomic_load(&flags[tid + 64],  __ATOMIC_RELAXED, __HIP_MEMORY_SCOPE_AGENT);
                    int f2 = __hip_atomic_load(&flags[tid + 128], __ATOMIC_RELAXED, __HIP_MEMORY_SCOPE_AGENT);
                    int f3 = __hip_atomic_load(&flags[tid + 192], __ATOMIC_RELAXED, __HIP_MEMORY_SCOPE_AGENT);
                    bool ok = (f0 >= target) && (f1 >= target) && (f2 >= target) && (f3 >= target);
                    if (__all(ok)) break;
                    __builtin_amdgcn_s_sleep(1);
                    if (++guard > (1 << 20)) break;   // hang bailout
                }
            }
            __syncthreads();
        }
    }

    // o-gate: c_511 still staged in LDS
    f4 accO = {0.f, 0.f, 0.f, 0.f};
#pragma unroll 4
    for (int kt = 0; kt < 32; kt++) {
        bh8 a  = *(const bh8*)(cs + abase + (((kt * 4 + quad) ^ asw) << 3));
        bh8 bo = *(const bh8*)(wop + (size_t)kt * 512);
        accO = __builtin_amdgcn_mfma_f32_16x16x32_bf16(a, bo, accO, 0, 0, 0);
    }
#pragma unroll
    for (int r = 0; r < 4; r++) {
        int b = row0 + msub * 16 + quad * 4 + r;
        int tok = x[b * SEQ + (SEQ - 1)];
        float o = sigf(OO[tok * H + hcol] + accO[r]);
        hb[(size_t)b * H + hcol] = tanhf(cn_keep[r]) * o;
    }
}

// ---------------- p = h @ Wph.T + bp ; out = log_softmax(p) -------------------------------
__global__ __launch_bounds__(128) void out_kernel(
    const float* __restrict__ hbuf, const float* __restrict__ Wph,
    const float* __restrict__ bp, float* __restrict__ out)
{
    const int b = blockIdx.x;
    const int j = threadIdx.x;
    __shared__ float hs[H];
    for (int t = j; t < H; t += 128) hs[t] = hbuf[(size_t)b * H + t];
    __syncthreads();
    const float4* w4 = (const float4*)(Wph + (size_t)j * H);
    const float4* h4 = (const float4*)hs;
    float acc = bp[j];
#pragma unroll 4
    for (int k = 0; k < H / 4; k++) {
        float4 a = w4[k], v = h4[k];
        acc += a.x * v.x + a.y * v.y + a.z * v.z + a.w * v.w;
    }
    __shared__ float red[128];
    red[j] = acc; __syncthreads();
    for (int off = 64; off > 0; off >>= 1) { if (j < off) red[j] = fmaxf(red[j], red[j + off]); __syncthreads(); }
    float m = red[0]; __syncthreads();
    red[j] = __expf(acc - m); __syncthreads();
    for (int off = 64; off > 0; off >>= 1) { if (j < off) red[j] += red[j + off]; __syncthreads(); }
    float lse = m + __logf(red[0]);
    out[(size_t)b * NC + j] = acc - lse;
}

extern "C" void kernel_launch(void* const* d_in, const int* in_sizes, int n_in,
                              void* d_out, int out_size, void* d_ws, size_t ws_size,
                              hipStream_t stream)
{
    const int*   x   = (const int*)d_in[0];
    const float* emb = (const float*)d_in[1];
    const float* Wcx = (const float*)d_in[2];
    const float* bc  = (const float*)d_in[3];
    const float* Wix = (const float*)d_in[4];
    const float* Wih = (const float*)d_in[5];
    const float* bi  = (const float*)d_in[6];
    const float* Wfx = (const float*)d_in[7];
    const float* Wfh = (const float*)d_in[8];
    const float* bf  = (const float*)d_in[9];
    const float* Wox = (const float*)d_in[10];
    const float* Woh = (const float*)d_in[11];
    const float* bo  = (const float*)d_in[12];
    const float* Wph = (const float*)d_in[13];
    const float* bp  = (const float*)d_in[14];
    float* out = (float*)d_out;

    char* wsb = (char*)d_ws;
    float* FF = (float*)(wsb + 0);                         // 512 KB
    float* II = (float*)(wsb + (512 << 10));
    float* OO = (float*)(wsb + (1024 << 10));
    float* G  = (float*)(wsb + (1536 << 10));
    float* hb = (float*)(wsb + (2048 << 10));              // 1 MB
    int*   flags = (int*)(wsb + (3072 << 10));             // 1 KB
    unsigned short* Wf_sw = (unsigned short*)(wsb + (4096 << 10));   // 2 MB each
    unsigned short* Wi_sw = (unsigned short*)(wsb + (6144 << 10));
    unsigned short* Wo_sw = (unsigned short*)(wsb + (8192 << 10));
    unsigned short* c16a  = (unsigned short*)(wsb + (10240 << 10));  // 512 KB each
    unsigned short* c16b  = (unsigned short*)(wsb + (10752 << 10));

    hipMemsetAsync(c16a, 0, (size_t)B * H * sizeof(unsigned short), stream);  // c_0 = 0
    hipMemsetAsync(flags, 0, NBLK * sizeof(int), stream);

    tables_kernel<<<dim3(NC, 4), 256, 0, stream>>>(emb, Wcx, bc, Wix, bi, Wfx, bf, Wox, bo,
                                                   FF, II, OO, G);
    swz_kernel<<<512, 256, 0, stream>>>(Wfh, Wf_sw);
    swz_kernel<<<512, 256, 0, stream>>>(Wih, Wi_sw);
    swz_kernel<<<512, 256, 0, stream>>>(Woh, Wo_sw);

    persist_kernel<<<NBLK, 256, 0, stream>>>(Wf_sw, Wi_sw, Wo_sw, FF, II, OO, G, x,
                                             c16a, c16b, hb, flags);

    out_kernel<<<B, 128, 0, stream>>>(hb, Wph, bp, out);
}